// Round 7
// baseline (145.346 us; speedup 1.0000x reference)
//
#include <hip/hip_runtime.h>
#include <hip/hip_bf16.h>

typedef __bf16 bf16;
typedef __bf16 bf16x4 __attribute__((ext_vector_type(4)));
typedef __bf16 bf16x8 __attribute__((ext_vector_type(8)));
typedef float  f32x16 __attribute__((ext_vector_type(16)));

#define S_  1024
#define D_  64
#define BQ  256          // 4 waves x 64 queries (R4 skeleton - best known)
#define BK  64
#define KT  (S_/BK)      // 16
#define QT  (S_/BQ)      // 4
#define LD  72           // bf16 stride: 144B rows, 16B-aligned

#define ZERO16 {0.f,0.f,0.f,0.f,0.f,0.f,0.f,0.f,0.f,0.f,0.f,0.f,0.f,0.f,0.f,0.f}

// S^T = K.Q^T ; O^T = V^T.P^T  with 32x32x16 MFMA, n=64 queries per wave.
// A/B: m|n=lane&31, k=(lane>>5)*8+j.  C/D: col=lane&31, row=(reg&3)+8*(reg>>2)+4*(lane>>5).
//
// KEY-PERMUTATION TRICK: softmax+PV contract over keys, so any key permutation
// applied consistently to (S rows, V^T cols) is legal. Store V key kk at LDS
// column rho(kk), rho = swap bits 2<->3. PV B-frags are then the lane's OWN
// exp'd QK output registers: no cross-lane exchange at all.
//
// R4 (kept): masked batches -> O = mean_k V cheap path; balanced static
// schedule. R6 (kept): stage -> barrier -> prefetch ordering.
// ROUND 7: half-tile software pipeline. With 1 wave/SIMD the chain
// QK->exp->PV was fully serial; now exp/PV of half-tile h overlaps the QK
// MFMAs of half-tile h+1 (separate VALU/MFMA pipes, no data dependency).
// Triple-buffered LDS keeps the deferred PV-half1(t-1) read race-free with
// one barrier per tile. Math identical to R6, just reordered.
__global__ __launch_bounds__(256, 2)
void fa_fwd(const float* __restrict__ Q, const float* __restrict__ K,
            const float* __restrict__ V, const int* __restrict__ mask,
            float* __restrict__ O)
{
    __shared__ bf16 ks[3][BK][LD];   // triple-buffered K tile [key][d]
    __shared__ bf16 vt[3][D_][LD];   // triple-buffered V^T tile [d][rho(key)]

    const int tid  = threadIdx.x;
    const int lane = tid & 63;
    const int w    = tid >> 6;
    const int l32  = lane & 31;
    const int hi   = lane >> 5;
    const int bid  = blockIdx.x;

    int um[8] = { mask[0] == 0, mask[1] == 0, mask[2] == 0, mask[3] == 0,
                  mask[4] == 0, mask[5] == 0, mask[6] == 0, mask[7] == 0 };
    int U = 0;
    #pragma unroll
    for (int i = 0; i < 8; ++i) U += um[i];
    const int nHeavy = 64 * U;
    const int nLight = 16 * (8 - U);

    int bh, qtile;
    bool light;
    if (bid < nHeavy) {
        const int xcd = bid & 7;
        const int r   = bid >> 3;
        qtile = r & 3;
        const int g   = r >> 2;
        const int bh_rank = (g << 3) | xcd;
        const int ub   = bh_rank >> 4;
        const int head = bh_rank & 15;
        int b = 0, cnt = 0;
        #pragma unroll
        for (int i = 0; i < 8; ++i) { if (um[i]) { if (cnt == ub) b = i; ++cnt; } }
        bh = b * 16 + head;
        light = false;
    } else if (bid < nHeavy + nLight) {
        const int lid    = bid - nHeavy;
        const int m_rank = lid >> 4;
        const int head   = lid & 15;
        int b = 0, cnt = 0;
        #pragma unroll
        for (int i = 0; i < 8; ++i) { if (!um[i]) { if (cnt == m_rank) b = i; ++cnt; } }
        bh = b * 16 + head;
        qtile = 0;
        light = true;
    } else {
        return;
    }

    const size_t base = (size_t)bh * (S_ * D_);

    if (light) {
        const float4* gvl = (const float4*)(V + base);
        float4*       gol = (float4*)(O + base);
        const int d4 = tid & 15;
        const int rg = tid >> 4;
        float4 acc = {0.f, 0.f, 0.f, 0.f};
        #pragma unroll 4
        for (int r = 0; r < 64; ++r) {
            float4 v = gvl[(rg * 64 + r) * 16 + d4];
            acc.x += v.x; acc.y += v.y; acc.z += v.z; acc.w += v.w;
        }
        float4 (*red)[16] = (float4(*)[16])&ks[0][0][0];
        red[rg][d4] = acc;
        __syncthreads();
        if (tid < 16) {
            float4 s = red[0][tid];
            #pragma unroll
            for (int g = 1; g < 16; ++g) {
                float4 t = red[g][tid];
                s.x += t.x; s.y += t.y; s.z += t.z; s.w += t.w;
            }
            const float sc = 1.0f / 1024.0f;
            s.x *= sc; s.y *= sc; s.z *= sc; s.w *= sc;
            red[0][tid] = s;
        }
        __syncthreads();
        float4 mv = red[0][d4];
        #pragma unroll 4
        for (int k = 0; k < 64; ++k)
            gol[(rg + 16 * k) * 16 + d4] = mv;
        return;
    }

    // ========== heavy path: R4 skeleton + half-tile software pipeline ======
    const int qW = qtile * BQ + w * 64;
    const float qscale = 0.1803368801111204f;    // log2e/8

    const int vkq = (tid >> 2) & 15;
    const int vkp = (vkq & 12) | ((vkq & 1) << 1) | ((vkq >> 1) & 1);
    const int vc4 = (tid & 3) + 4 * w;
    const float4* gk = (const float4*)(K + base);
    const float4* gv = (const float4*)(V + base);

    float4 kr[4], vr[4];
    #pragma unroll
    for (int it = 0; it < 4; ++it) kr[it] = gk[it * 256 + tid];
    #pragma unroll
    for (int r = 0; r < 4; ++r)    vr[r]  = gv[(vkq * 4 + r) * 16 + vc4];

    bf16x8 qf[2][4];
    #pragma unroll
    for (int nt = 0; nt < 2; ++nt) {
        const float* qp = Q + base + (size_t)(qW + nt * 32 + l32) * D_ + hi * 8;
        #pragma unroll
        for (int kc = 0; kc < 4; ++kc) {
            float4 a = *(const float4*)(qp + kc * 16);
            float4 c = *(const float4*)(qp + kc * 16 + 4);
            bf16x8 f;
            f[0] = (bf16)(a.x * qscale); f[1] = (bf16)(a.y * qscale);
            f[2] = (bf16)(a.z * qscale); f[3] = (bf16)(a.w * qscale);
            f[4] = (bf16)(c.x * qscale); f[5] = (bf16)(c.y * qscale);
            f[6] = (bf16)(c.z * qscale); f[7] = (bf16)(c.w * qscale);
            qf[nt][kc] = f;
        }
    }

    f32x16 o[2][2];
    #pragma unroll
    for (int dm = 0; dm < 2; ++dm)
        #pragma unroll
        for (int nt = 0; nt < 2; ++nt) o[dm][nt] = (f32x16)ZERO16;
    float lsum[2] = {0.f, 0.f};

    auto stage_to = [&](int bsel) {
        bf16 (*ksb)[LD] = ks[bsel];
        bf16 (*vtb)[LD] = vt[bsel];
        #pragma unroll
        for (int it = 0; it < 4; ++it) {
            int i = it * 256 + tid;
            int row = i >> 4, c4 = i & 15;
            bf16x4 hk = {(bf16)kr[it].x, (bf16)kr[it].y, (bf16)kr[it].z, (bf16)kr[it].w};
            *(bf16x4*)&ksb[row][c4 * 4] = hk;
        }
        bf16x4 t0 = {(bf16)vr[0].x, (bf16)vr[1].x, (bf16)vr[2].x, (bf16)vr[3].x};
        bf16x4 t1 = {(bf16)vr[0].y, (bf16)vr[1].y, (bf16)vr[2].y, (bf16)vr[3].y};
        bf16x4 t2 = {(bf16)vr[0].z, (bf16)vr[1].z, (bf16)vr[2].z, (bf16)vr[3].z};
        bf16x4 t3 = {(bf16)vr[0].w, (bf16)vr[1].w, (bf16)vr[2].w, (bf16)vr[3].w};
        *(bf16x4*)&vtb[vc4 * 4 + 0][vkp * 4] = t0;
        *(bf16x4*)&vtb[vc4 * 4 + 1][vkp * 4] = t1;
        *(bf16x4*)&vtb[vc4 * 4 + 2][vkp * 4] = t2;
        *(bf16x4*)&vtb[vc4 * 4 + 3][vkp * 4] = t3;
    };
    auto prefetch_t = [&](int t) {
        #pragma unroll
        for (int it = 0; it < 4; ++it) kr[it] = gk[t * 1024 + it * 256 + tid];
        #pragma unroll
        for (int r = 0; r < 4; ++r)    vr[r]  = gv[t * 1024 + (vkq * 4 + r) * 16 + vc4];
    };

    auto qk_half = [&](int bsel, int rowoff, f32x16& s_0, f32x16& s_1) {
        bf16 (*ksb)[LD] = ks[bsel];
        #pragma unroll
        for (int kc = 0; kc < 4; ++kc) {
            bf16x8 kf = *(const bf16x8*)&ksb[rowoff + l32][kc * 16 + hi * 8];
            s_0 = __builtin_amdgcn_mfma_f32_32x32x16_bf16(kf, qf[0][kc], s_0, 0, 0, 0);
            s_1 = __builtin_amdgcn_mfma_f32_32x32x16_bf16(kf, qf[1][kc], s_1, 0, 0, 0);
        }
    };

    auto mkpf = [&](const f32x16& sv, bf16x8& fA, bf16x8& fB, float& ls) {
        bf16x8 a, c;
        #pragma unroll
        for (int i = 0; i < 8; ++i) {
            float e0 = __builtin_amdgcn_exp2f(sv[i]);
            float e1 = __builtin_amdgcn_exp2f(sv[8 + i]);
            ls += e0 + e1;
            a[i] = (bf16)e0;
            c[i] = (bf16)e1;
        }
        fA = a; fB = c;
    };

    auto exp_pv_half = [&](const f32x16& s_0, const f32x16& s_1, int bsel, int kc0) {
        bf16x8 a0, a1, b0, b1;
        mkpf(s_0, a0, b0, lsum[0]);
        mkpf(s_1, a1, b1, lsum[1]);
        bf16 (*vtb)[LD] = vt[bsel];
        bf16x8 v0 = *(const bf16x8*)&vtb[l32][kc0 * 16 + hi * 8];
        bf16x8 v1 = *(const bf16x8*)&vtb[32 + l32][kc0 * 16 + hi * 8];
        o[0][0] = __builtin_amdgcn_mfma_f32_32x32x16_bf16(v0, a0, o[0][0], 0, 0, 0);
        o[0][1] = __builtin_amdgcn_mfma_f32_32x32x16_bf16(v0, a1, o[0][1], 0, 0, 0);
        o[1][0] = __builtin_amdgcn_mfma_f32_32x32x16_bf16(v1, a0, o[1][0], 0, 0, 0);
        o[1][1] = __builtin_amdgcn_mfma_f32_32x32x16_bf16(v1, a1, o[1][1], 0, 0, 0);
        bf16x8 w0 = *(const bf16x8*)&vtb[l32][(kc0 + 1) * 16 + hi * 8];
        bf16x8 w1 = *(const bf16x8*)&vtb[32 + l32][(kc0 + 1) * 16 + hi * 8];
        o[0][0] = __builtin_amdgcn_mfma_f32_32x32x16_bf16(w0, b0, o[0][0], 0, 0, 0);
        o[0][1] = __builtin_amdgcn_mfma_f32_32x32x16_bf16(w0, b1, o[0][1], 0, 0, 0);
        o[1][0] = __builtin_amdgcn_mfma_f32_32x32x16_bf16(w1, b0, o[1][0], 0, 0, 0);
        o[1][1] = __builtin_amdgcn_mfma_f32_32x32x16_bf16(w1, b1, o[1][1], 0, 0, 0);
    };

    f32x16 sA0, sA1, sB0, sB1;

    // -------- prologue: tile 0 --------
    stage_to(0);
    __syncthreads();
    prefetch_t(1);
    sA0 = (f32x16)ZERO16; sA1 = (f32x16)ZERO16;
    qk_half(0, 0,  sA0, sA1);        // half0(0)
    sB0 = (f32x16)ZERO16; sB1 = (f32x16)ZERO16;
    qk_half(0, 32, sB0, sB1);        // half1(0), consumed in iter kt=1
    exp_pv_half(sA0, sA1, 0, 0);     // exp+PV half0(0)

    int bs = 1, bp = 0;              // stage buf (kt%3), prev buf ((kt-1)%3)
    for (int kt = 1; kt < KT; ++kt) {
        stage_to(bs);
        __syncthreads();
        prefetch_t((kt + 1 < KT) ? (kt + 1) : kt);
        sA0 = (f32x16)ZERO16; sA1 = (f32x16)ZERO16;
        qk_half(bs, 0, sA0, sA1);            // QK half0(kt)
        exp_pv_half(sB0, sB1, bp, 2);        // exp+PV half1(kt-1): fills QK shadow
        sB0 = (f32x16)ZERO16; sB1 = (f32x16)ZERO16;
        qk_half(bs, 32, sB0, sB1);           // QK half1(kt)
        exp_pv_half(sA0, sA1, bs, 0);        // exp+PV half0(kt)
        bp = bs; bs = (bs == 2) ? 0 : bs + 1;
    }
    exp_pv_half(sB0, sB1, bp, 2);            // epilogue: half1(15)

    #pragma unroll
    for (int nt = 0; nt < 2; ++nt) {
        float lv = lsum[nt] + __shfl_xor(lsum[nt], 32);
        float inv = 1.0f / lv;
        float* op = O + base + (size_t)(qW + nt * 32 + l32) * D_ + hi * 4;
        #pragma unroll
        for (int g = 0; g < 4; ++g) {
            float4 a = { o[0][nt][g * 4 + 0] * inv, o[0][nt][g * 4 + 1] * inv,
                         o[0][nt][g * 4 + 2] * inv, o[0][nt][g * 4 + 3] * inv };
            *(float4*)(op + g * 8) = a;
            float4 c = { o[1][nt][g * 4 + 0] * inv, o[1][nt][g * 4 + 1] * inv,
                         o[1][nt][g * 4 + 2] * inv, o[1][nt][g * 4 + 3] * inv };
            *(float4*)(op + 32 + g * 8) = c;
        }
    }
}

extern "C" void kernel_launch(void* const* d_in, const int* in_sizes, int n_in,
                              void* d_out, int out_size, void* d_ws, size_t ws_size,
                              hipStream_t stream)
{
    const float* Q    = (const float*)d_in[0];
    const float* K    = (const float*)d_in[1];
    const float* V    = (const float*)d_in[2];
    const int*   mask = (const int*)d_in[3];
    float*       O    = (float*)d_out;

    dim3 grid(8 * 16 * QT);
    fa_fwd<<<grid, 256, 0, stream>>>(Q, K, V, mask, O);
}

// Round 8
// 133.800 us; speedup vs baseline: 1.0863x; 1.0863x over previous
//
#include <hip/hip_runtime.h>
#include <hip/hip_bf16.h>

typedef __bf16 bf16;
typedef __bf16 bf16x4 __attribute__((ext_vector_type(4)));
typedef __bf16 bf16x8 __attribute__((ext_vector_type(8)));
typedef float  f32x16 __attribute__((ext_vector_type(16)));

#define S_  1024
#define D_  64
#define BQ  256          // consumer tile: 4 waves x 64 queries (R4 geometry)
#define BK  64
#define KT  (S_/BK)      // 16
#define QT  (S_/BQ)      // 4
#define LD  72           // bf16 stride: 144B rows, 16B-aligned

#define ZERO16 {0.f,0.f,0.f,0.f,0.f,0.f,0.f,0.f,0.f,0.f,0.f,0.f,0.f,0.f,0.f,0.f}

// S^T = K.Q^T ; O^T = V^T.P^T  with 32x32x16 MFMA, n=64 queries per wave.
// A/B: m|n=lane&31, k=(lane>>5)*8+j.  C/D: col=lane&31, row=(reg&3)+8*(reg>>2)+4*(lane>>5).
//
// KEY-PERMUTATION TRICK: softmax+PV contract over keys, so any key permutation
// applied consistently to (S rows, V^T cols) is legal. Store V key kk at LDS
// column rho(kk), rho = swap bits 2<->3. PV B-frags are then the lane's OWN
// exp'd QK output registers: no cross-lane exchange at all.
//
// R4 (kept): masked batches -> O = mean_k V cheap path; balanced static
// schedule (heavy items take lowest bids -> one heavy block per CU first).
// ROUND 8: producer/consumer wave specialization. Per-tile consumer chain
// was stage(+vmcnt) -> barrier -> QK -> exp -> PV, fully serial at 1 wave/
// SIMD. Now 512 threads: waves 0-3 = consumers (pure barrier->QK->exp->PV,
// zero vmem ops in loop), waves 4-7 = producers (exact R4 staging+prefetch,
// one per SIMD so issue load is balanced). Producer stages tile t+1 into
// buf((t+1)&1) while consumers compute tile t from buf(t&1); one barrier
// per tile; double-buffer invariant unchanged. LDS traffic per CU unchanged
// (no redundancy added - the R3/R5 mistake).
__global__ __launch_bounds__(512, 2)
void fa_fwd(const float* __restrict__ Q, const float* __restrict__ K,
            const float* __restrict__ V, const int* __restrict__ mask,
            float* __restrict__ O)
{
    __shared__ bf16 ks[2][BK][LD];   // double-buffered K tile [key][d]
    __shared__ bf16 vt[2][D_][LD];   // double-buffered V^T tile [d][rho(key)]

    const int tid  = threadIdx.x;
    const int lane = tid & 63;
    const int w    = tid >> 6;       // 0..7
    const int l32  = lane & 31;
    const int hi   = lane >> 5;
    const int bid  = blockIdx.x;

    // ---- schedule from mask (uniform scalar work) ----
    int um[8] = { mask[0] == 0, mask[1] == 0, mask[2] == 0, mask[3] == 0,
                  mask[4] == 0, mask[5] == 0, mask[6] == 0, mask[7] == 0 };
    int U = 0;
    #pragma unroll
    for (int i = 0; i < 8; ++i) U += um[i];
    const int nHeavy = 64 * U;            // (unmasked bh) x 4 qtiles
    const int nLight = 16 * (8 - U);      // one per masked bh

    int bh, qtile;
    bool light;
    if (bid < nHeavy) {
        const int xcd = bid & 7;
        const int r   = bid >> 3;
        qtile = r & 3;
        const int g   = r >> 2;
        const int bh_rank = (g << 3) | xcd;
        const int ub   = bh_rank >> 4;
        const int head = bh_rank & 15;
        int b = 0, cnt = 0;
        #pragma unroll
        for (int i = 0; i < 8; ++i) { if (um[i]) { if (cnt == ub) b = i; ++cnt; } }
        bh = b * 16 + head;
        light = false;
    } else if (bid < nHeavy + nLight) {
        const int lid    = bid - nHeavy;
        const int m_rank = lid >> 4;
        const int head   = lid & 15;
        int b = 0, cnt = 0;
        #pragma unroll
        for (int i = 0; i < 8; ++i) { if (!um[i]) { if (cnt == m_rank) b = i; ++cnt; } }
        bh = b * 16 + head;
        qtile = 0;
        light = true;
    } else {
        return;
    }

    const size_t base = (size_t)bh * (S_ * D_);

    if (light) {
        // ---- masked bh: O[q,:] = mean_k V[k,:] for all q (exact); 512 thr ----
        const float4* gvl = (const float4*)(V + base);
        float4*       gol = (float4*)(O + base);
        const int d4 = tid & 15;              // float4 column
        const int rg = tid >> 4;              // 32 row groups of 32 rows
        float4 acc = {0.f, 0.f, 0.f, 0.f};
        #pragma unroll 4
        for (int r = 0; r < 32; ++r) {
            float4 v = gvl[(rg * 32 + r) * 16 + d4];
            acc.x += v.x; acc.y += v.y; acc.z += v.z; acc.w += v.w;
        }
        float4 (*red)[16] = (float4(*)[16])&ks[0][0][0];   // 8KB LDS alias
        red[rg][d4] = acc;
        __syncthreads();
        if (tid < 16) {
            float4 s = red[0][tid];
            #pragma unroll
            for (int g = 1; g < 32; ++g) {
                float4 t = red[g][tid];
                s.x += t.x; s.y += t.y; s.z += t.z; s.w += t.w;
            }
            const float sc = 1.0f / 1024.0f;
            s.x *= sc; s.y *= sc; s.z *= sc; s.w *= sc;
            red[0][tid] = s;
        }
        __syncthreads();
        float4 mv = red[0][d4];
        #pragma unroll 4
        for (int k = 0; k < 32; ++k)
            gol[(rg + 32 * k) * 16 + d4] = mv;
        return;
    }

    // ========== heavy path: 4 consumer waves + 4 producer waves ============
    const bool consumer = (w < 4);
    const float qscale = 0.1803368801111204f;    // log2e/8 (unmasked here)

    if (consumer) {
        // ---------------- CONSUMER: pure compute loop ----------------
        const int qW = qtile * BQ + w * 64;

        // Q B-fragments for 2 n-tiles: B[k=d][n=q]
        bf16x8 qf[2][4];
        #pragma unroll
        for (int nt = 0; nt < 2; ++nt) {
            const float* qp = Q + base + (size_t)(qW + nt * 32 + l32) * D_ + hi * 8;
            #pragma unroll
            for (int kc = 0; kc < 4; ++kc) {
                float4 a = *(const float4*)(qp + kc * 16);
                float4 c = *(const float4*)(qp + kc * 16 + 4);
                bf16x8 f;
                f[0] = (bf16)(a.x * qscale); f[1] = (bf16)(a.y * qscale);
                f[2] = (bf16)(a.z * qscale); f[3] = (bf16)(a.w * qscale);
                f[4] = (bf16)(c.x * qscale); f[5] = (bf16)(c.y * qscale);
                f[6] = (bf16)(c.z * qscale); f[7] = (bf16)(c.w * qscale);
                qf[nt][kc] = f;
            }
        }

        f32x16 o[2][2];                  // [d-tile][n-tile]
        #pragma unroll
        for (int dm = 0; dm < 2; ++dm)
            #pragma unroll
            for (int nt = 0; nt < 2; ++nt) o[dm][nt] = (f32x16)ZERO16;
        float lsum[2] = {0.f, 0.f};

        auto mkpf = [&](const f32x16& sv, bf16x8& fA, bf16x8& fB, float& ls) {
            bf16x8 a, c;
            #pragma unroll
            for (int i = 0; i < 8; ++i) {
                float e0 = __builtin_amdgcn_exp2f(sv[i]);
                float e1 = __builtin_amdgcn_exp2f(sv[8 + i]);
                ls += e0 + e1;
                a[i] = (bf16)e0;
                c[i] = (bf16)e1;
            }
            fA = a; fB = c;
        };

        __syncthreads();                 // tile 0 staged by producers

        for (int kt = 0; kt < KT; ++kt) {
            bf16 (*ksb)[LD] = ks[kt & 1];
            bf16 (*vtb)[LD] = vt[kt & 1];

            // S^T = K.Q^T : 2 m-tiles (keys) x 2 n-tiles (queries)
            f32x16 s00 = ZERO16, s01 = ZERO16, s10 = ZERO16, s11 = ZERO16;
            #pragma unroll
            for (int kc = 0; kc < 4; ++kc) {
                bf16x8 k0 = *(const bf16x8*)&ksb[l32][kc * 16 + hi * 8];
                bf16x8 k1 = *(const bf16x8*)&ksb[32 + l32][kc * 16 + hi * 8];
                s00 = __builtin_amdgcn_mfma_f32_32x32x16_bf16(k0, qf[0][kc], s00, 0, 0, 0);
                s01 = __builtin_amdgcn_mfma_f32_32x32x16_bf16(k0, qf[1][kc], s01, 0, 0, 0);
                s10 = __builtin_amdgcn_mfma_f32_32x32x16_bf16(k1, qf[0][kc], s10, 0, 0, 0);
                s11 = __builtin_amdgcn_mfma_f32_32x32x16_bf16(k1, qf[1][kc], s11, 0, 0, 0);
            }

            // exp -> PV B-frags, all in-lane (key-permutation trick)
            bf16x8 pf[4][2];             // [kc][nt]
            mkpf(s00, pf[0][0], pf[1][0], lsum[0]);
            mkpf(s01, pf[0][1], pf[1][1], lsum[1]);
            mkpf(s10, pf[2][0], pf[3][0], lsum[0]);
            mkpf(s11, pf[2][1], pf[3][1], lsum[1]);

            // O^T += V^T.P^T
            #pragma unroll
            for (int kc = 0; kc < 4; ++kc) {
                bf16x8 v0 = *(const bf16x8*)&vtb[l32][kc * 16 + hi * 8];
                bf16x8 v1 = *(const bf16x8*)&vtb[32 + l32][kc * 16 + hi * 8];
                o[0][0] = __builtin_amdgcn_mfma_f32_32x32x16_bf16(v0, pf[kc][0], o[0][0], 0, 0, 0);
                o[0][1] = __builtin_amdgcn_mfma_f32_32x32x16_bf16(v0, pf[kc][1], o[0][1], 0, 0, 0);
                o[1][0] = __builtin_amdgcn_mfma_f32_32x32x16_bf16(v1, pf[kc][0], o[1][0], 0, 0, 0);
                o[1][1] = __builtin_amdgcn_mfma_f32_32x32x16_bf16(v1, pf[kc][1], o[1][1], 0, 0, 0);
            }

            __syncthreads();             // tile kt+1 now staged
        }

        // epilogue: lane holds half the keys' sum; one cross-half add
        #pragma unroll
        for (int nt = 0; nt < 2; ++nt) {
            float lv = lsum[nt] + __shfl_xor(lsum[nt], 32);
            float inv = 1.0f / lv;
            float* op = O + base + (size_t)(qW + nt * 32 + l32) * D_ + hi * 4;
            #pragma unroll
            for (int g = 0; g < 4; ++g) {
                float4 a = { o[0][nt][g * 4 + 0] * inv, o[0][nt][g * 4 + 1] * inv,
                             o[0][nt][g * 4 + 2] * inv, o[0][nt][g * 4 + 3] * inv };
                *(float4*)(op + g * 8) = a;           // d = 4hi + 8g + r
                float4 c = { o[1][nt][g * 4 + 0] * inv, o[1][nt][g * 4 + 1] * inv,
                             o[1][nt][g * 4 + 2] * inv, o[1][nt][g * 4 + 3] * inv };
                *(float4*)(op + 32 + g * 8) = c;      // d = 32 + 4hi + 8g + r
            }
        }
    } else {
        // ---------------- PRODUCER: staging + prefetch loop ----------------
        const int t2  = tid - 256;          // 0..255, matches R4 staging index
        const int vkq = (t2 >> 2) & 15;     // V transpose: 4-key group (natural)
        const int vkp = (vkq & 12) | ((vkq & 1) << 1) | ((vkq >> 1) & 1); // rho
        const int vc4 = (t2 & 3) + 4 * ((t2 >> 6) & 3);   // d-chunk
        const float4* gk = (const float4*)(K + base);
        const float4* gv = (const float4*)(V + base);

        float4 kr[4], vr[4];
        auto prefetch_t = [&](int t) {
            #pragma unroll
            for (int it = 0; it < 4; ++it) kr[it] = gk[t * 1024 + it * 256 + t2];
            #pragma unroll
            for (int r = 0; r < 4; ++r)    vr[r]  = gv[t * 1024 + (vkq * 4 + r) * 16 + vc4];
        };
        auto stage_to = [&](int bsel) {
            bf16 (*ksb)[LD] = ks[bsel];
            bf16 (*vtb)[LD] = vt[bsel];
            #pragma unroll
            for (int it = 0; it < 4; ++it) {
                int i = it * 256 + t2;
                int row = i >> 4, c4 = i & 15;
                bf16x4 hk = {(bf16)kr[it].x, (bf16)kr[it].y, (bf16)kr[it].z, (bf16)kr[it].w};
                *(bf16x4*)&ksb[row][c4 * 4] = hk;
            }
            bf16x4 t0 = {(bf16)vr[0].x, (bf16)vr[1].x, (bf16)vr[2].x, (bf16)vr[3].x};
            bf16x4 t1 = {(bf16)vr[0].y, (bf16)vr[1].y, (bf16)vr[2].y, (bf16)vr[3].y};
            bf16x4 t2v = {(bf16)vr[0].z, (bf16)vr[1].z, (bf16)vr[2].z, (bf16)vr[3].z};
            bf16x4 t3 = {(bf16)vr[0].w, (bf16)vr[1].w, (bf16)vr[2].w, (bf16)vr[3].w};
            *(bf16x4*)&vtb[vc4 * 4 + 0][vkp * 4] = t0;
            *(bf16x4*)&vtb[vc4 * 4 + 1][vkp * 4] = t1;
            *(bf16x4*)&vtb[vc4 * 4 + 2][vkp * 4] = t2v;
            *(bf16x4*)&vtb[vc4 * 4 + 3][vkp * 4] = t3;
        };

        // prologue: stage tile 0, prefetch tile 1
        prefetch_t(0);
        stage_to(0);
        prefetch_t(1);
        __syncthreads();                 // release consumers into tile 0

        for (int kt = 0; kt < KT; ++kt) {
            // stage tile kt+1 into the other buffer while consumers compute kt
            if (kt + 1 < KT) {
                stage_to((kt + 1) & 1);
                if (kt + 2 < KT) prefetch_t(kt + 2);
            }
            __syncthreads();
        }
        // producers exit (no epilogue)
    }
}

extern "C" void kernel_launch(void* const* d_in, const int* in_sizes, int n_in,
                              void* d_out, int out_size, void* d_ws, size_t ws_size,
                              hipStream_t stream)
{
    const float* Q    = (const float*)d_in[0];
    const float* K    = (const float*)d_in[1];
    const float* V    = (const float*)d_in[2];
    const int*   mask = (const int*)d_in[3];
    float*       O    = (float*)d_out;

    // grid covers worst case: all-unmasked = 512 heavy blocks (surplus exits)
    dim3 grid(8 * 16 * QT);
    fa_fwd<<<grid, 512, 0, stream>>>(Q, K, V, mask, O);
}